// Round 6
// baseline (603.502 us; speedup 1.0000x reference)
//
#include <hip/hip_runtime.h>
#include <stdint.h>

#define B_    64
#define CIN   64
#define L_IN  16384
#define COUT  128
#define K_    7
#define LPA   16416          // padded A row stride (u64 words)
#define LOUT  8189
#define TOUT  8
#define CO_PER_BLK 16
#define REC_W 16             // u64 words per co record

// ---------------- pack_A2: ballot-transpose sign packing ----------------
// Each wave: 64ci x 32col tile. Stage f32 to LDS (stride 33 dwords -> 2-way max,
// free), lane=ci reads column c, __ballot(v<0) = packed word (wave-uniform),
// collected per-column via predicated select.
__global__ __launch_bounds__(256) void pack_A2(const float* __restrict__ I,
                                               uint64_t* __restrict__ A) {
    __shared__ uint32_t lds[4][64 * 33];
    const int b  = blockIdx.y;
    const int ct = blockIdx.x;            // col-tile of 128
    const int t  = threadIdx.x;
    const int wv = t >> 6, ln = t & 63;
    const int col0 = ct * 128 + wv * 32;  // this wave's 32 columns
    uint32_t* ldsw = lds[wv];

    // stage: per pass, 8 rows x 128B contiguous segments
    const int r0 = ln >> 3, cq = ln & 7;
    const uint32_t* Ibase = (const uint32_t*)(I + (size_t)b * CIN * L_IN);
#pragma unroll
    for (int p = 0; p < 8; ++p) {
        int row = p * 8 + r0;
        uint4 v = *(const uint4*)(Ibase + (size_t)row * L_IN + col0 + cq * 4);
        int base = row * 33 + cq * 4;
        ldsw[base + 0] = v.x; ldsw[base + 1] = v.y;
        ldsw[base + 2] = v.z; ldsw[base + 3] = v.w;
    }
    __syncthreads();

    uint32_t accL = 0, accH = 0;
#pragma unroll
    for (int c = 0; c < 32; ++c) {
        uint32_t u = ldsw[ln * 33 + c];                  // lane = ci
        unsigned long long m = __ballot((int)(u >> 31)); // bit ci = sign, wave-uniform
        if (ln == c) { accL = (uint32_t)m; accH = (uint32_t)(m >> 32); }
    }
    if (ln < 32) {
        uint64_t w = ((uint64_t)accH << 32) | accL;
        A[(size_t)b * LPA + 3 + col0 + ln] = w;          // word index = col+3
    }
    // pad words: sign(-1.0) = all ones
    if (ct == 0 && t < 6)
        A[(size_t)b * LPA + (t < 3 ? t : L_IN + t)] = ~0ULL;
}

// ---------------- pack_W2: per-co 128B record ----------------
// rec[0..6] = packed weight words; rec[7] = itp | itm<<32 (int thresholds in s-domain);
// rec[8] = ps_bits | ms_bits<<32.  pooled = 448-2*smin:
//   pooled >  thr  <=>  smin <= ceil((448-thr)/2)-1
//   pooled >= 0    <=>  smin <= 224
__global__ __launch_bounds__(128) void pack_W2(const float* __restrict__ W,
                                               const float* __restrict__ tp_,
                                               const float* __restrict__ tm_,
                                               const float* __restrict__ ps_,
                                               const float* __restrict__ ms_,
                                               uint64_t* __restrict__ Rp) {
    int co = threadIdx.x;
    if (co >= COUT) return;
    uint64_t* rec = Rp + (size_t)co * REC_W;
#pragma unroll
    for (int k = 0; k < K_; ++k) {
        uint64_t acc = 0;
        for (int ci = 0; ci < CIN; ++ci) {
            uint32_t s = __float_as_uint(W[(size_t)co * CIN * K_ + ci * K_ + k]) >> 31;
            acc |= (uint64_t)s << ci;
        }
        rec[k] = acc;
    }
    int itp = (int)ceilf((448.0f - tp_[co]) * 0.5f) - 1;
    int itm = (int)ceilf((448.0f - tm_[co]) * 0.5f) - 1;
    rec[7] = (uint64_t)(uint32_t)itp | ((uint64_t)(uint32_t)itm << 32);
    rec[8] = (uint64_t)__float_as_uint(ps_[co]) |
             ((uint64_t)__float_as_uint(ms_[co]) << 32);
}

// ---------------- bconv2: binary conv + maxpool(7,2) + threshold ----------------
__global__ __launch_bounds__(256, 4) void bconv2(
    const uint64_t* __restrict__ A, const uint64_t* __restrict__ Rp,
    uint32_t* __restrict__ out)
{
    const int cg = blockIdx.x;   // 0..7 co-group
    const int lc = blockIdx.y;   // 0..3 l-chunk
    const int b  = blockIdx.z;   // 0..63
    const int t  = threadIdx.x;
    int out0 = lc * 2048 + t * TOUT;
    if (out0 > LOUT - TOUT) out0 = LOUT - TOUT;   // duplicates write identical values

    // 27-word window, 16B-aligned pair loads
    const ulonglong2* Ab2 = (const ulonglong2*)(A + (size_t)b * LPA + 2 * out0);
    uint64_t a[27];
#pragma unroll
    for (int j = 0; j < 13; ++j) { ulonglong2 v = Ab2[j]; a[2*j] = v.x; a[2*j+1] = v.y; }
    a[26] = ((const uint64_t*)Ab2)[26];

    uint32_t* op = out + ((size_t)(b * COUT + cg * CO_PER_BLK)) * LOUT + out0;

#pragma unroll 2
    for (int ci_ = 0; ci_ < CO_PER_BLK; ++ci_) {
        const uint64_t* rec = Rp + (size_t)(cg * CO_PER_BLK + ci_) * REC_W;  // uniform -> s_load
        const uint64_t w0 = rec[0], w1 = rec[1], w2 = rec[2], w3 = rec[3],
                       w4 = rec[4], w5 = rec[5], w6 = rec[6];
        const uint64_t thr = rec[7], sgn = rec[8];
        const int itp = (int)(uint32_t)thr, itm = (int)(uint32_t)(thr >> 32);
        const uint32_t psb = (uint32_t)sgn,  msb = (uint32_t)(sgn >> 32);
        const uint32_t npsb = psb ^ 0x80000000u, nmsb = msb ^ 0x80000000u;

        int s[2 * TOUT + 5];
#pragma unroll
        for (int j = 0; j < 2 * TOUT + 5; ++j) {
            int acc;
            acc  = __popcll(a[j + 0] ^ w0);
            acc += __popcll(a[j + 1] ^ w1);
            acc += __popcll(a[j + 2] ^ w2);
            acc += __popcll(a[j + 3] ^ w3);
            acc += __popcll(a[j + 4] ^ w4);
            acc += __popcll(a[j + 5] ^ w5);
            acc += __popcll(a[j + 6] ^ w6);
            s[j] = acc;
        }

        int p[TOUT + 2];
#pragma unroll
        for (int i = 0; i < TOUT + 2; ++i) p[i] = min(s[2 * i], s[2 * i + 1]);

#pragma unroll
        for (int o = 0; o < TOUT; ++o) {
            int smin = min(min(p[o], p[o + 1]), min(p[o + 2], s[2 * o + 6]));
            uint32_t pos = (smin <= itp) ? psb : npsb;
            uint32_t neg = (smin <= itm) ? msb : nmsb;
            op[o] = (smin <= 224) ? pos : neg;
        }
        op += LOUT;
    }
}

extern "C" void kernel_launch(void* const* d_in, const int* in_sizes, int n_in,
                              void* d_out, int out_size, void* d_ws, size_t ws_size,
                              hipStream_t stream) {
    const float* I  = (const float*)d_in[0];
    const float* W  = (const float*)d_in[1];
    const float* tp = (const float*)d_in[2];
    const float* tm = (const float*)d_in[3];
    const float* ps = (const float*)d_in[4];
    const float* ms = (const float*)d_in[5];
    uint32_t* out = (uint32_t*)d_out;

    uint64_t* Rp = (uint64_t*)d_ws;                                   // 16 KB
    uint64_t* A  = (uint64_t*)((char*)d_ws + COUT * REC_W * sizeof(uint64_t));

    hipLaunchKernelGGL(pack_W2, dim3(1), dim3(128), 0, stream, W, tp, tm, ps, ms, Rp);
    hipLaunchKernelGGL(pack_A2, dim3(128, B_), dim3(256), 0, stream, I, A);
    hipLaunchKernelGGL(bconv2, dim3(8, 4, B_), dim3(256), 0, stream, A, Rp, out);
}